// Round 11
// baseline (179.671 us; speedup 1.0000x reference)
//
#include <hip/hip_runtime.h>
#include <hip/hip_bf16.h>
#include <math.h>

#define BB   16      // batch
#define NC   1024    // candidates per query row
#define QL   32      // query tokens
#define HD   128     // embed dim
#define DLN  64      // doc tokens per doc
#define RK   128     // rescore set size per row (pow2, >= k=100 with margin)
#define CPB  32      // candidates per block in the screen kernel

typedef __attribute__((ext_vector_type(8))) short bf16x8;   // 8 bf16 (4 VGPRs)
typedef __attribute__((ext_vector_type(4))) float f32x4;    // MFMA accumulator
typedef __attribute__((ext_vector_type(4))) double f64x4;   // f64 MFMA accum

// ---------------------------------------------------------------------------
// K0: precompute bf16(q) for the MFMA screen.
// ---------------------------------------------------------------------------
__global__ __launch_bounds__(256) void k_qprep(
    const float* __restrict__ q, unsigned short* __restrict__ qhi)
{
    int i = blockIdx.x * 256 + threadIdx.x;          // BB*QL*HD = 65536
    float v = q[i];
    __hip_bfloat16 h = __float2bfloat16(v);
    qhi[i] = *reinterpret_cast<unsigned short*>(&h);
}

// ---------------------------------------------------------------------------
// K1: pids = emb2pid[topk]; validate; per-row descending bitonic sort; dedup.
// (R9 version, proven.)
// ---------------------------------------------------------------------------
__global__ __launch_bounds__(1024) void k_gather_sort_dedup(
    const int* __restrict__ topk, const int* __restrict__ emb2pid,
    int n_emb, int n_docs, int* __restrict__ pids_out)
{
    const int b = blockIdx.x;
    const int t = threadIdx.x;
    __shared__ int s[NC];

    int idx = topk[b * NC + t];
    int pid = (idx >= 0 && idx < n_emb) ? emb2pid[idx] : -1;
    if (pid < 0 || pid >= n_docs) pid = -1;
    s[t] = pid;
    __syncthreads();

    for (int k2 = 2; k2 <= NC; k2 <<= 1) {
        for (int j = k2 >> 1; j > 0; j >>= 1) {
            int ixj = t ^ j;
            if (ixj > t) {
                int a = s[t], c = s[ixj];
                bool desc = ((t & k2) == 0);
                if (desc ? (a < c) : (a > c)) { s[t] = c; s[ixj] = a; }
            }
            __syncthreads();
        }
    }
    int v = s[t];
    pids_out[b * NC + t] = (t > 0 && v == s[t - 1]) ? -1 : v;
}

// ---------------------------------------------------------------------------
// RTZ f32 -> bf16 x8 via v_perm high-16 extraction (4 ops). Screen-only:
// unbiased error std ~0.004 vs ~0.11 selection margin; rescore is exact f64.
// ---------------------------------------------------------------------------
__device__ __forceinline__ bf16x8 cvt8_rtz(float4 a, float4 b)
{
    union { unsigned int u[4]; bf16x8 v; } r;
    r.u[0] = __builtin_amdgcn_perm(__float_as_uint(a.y), __float_as_uint(a.x), 0x07060302u);
    r.u[1] = __builtin_amdgcn_perm(__float_as_uint(a.w), __float_as_uint(a.z), 0x07060302u);
    r.u[2] = __builtin_amdgcn_perm(__float_as_uint(b.y), __float_as_uint(b.x), 0x07060302u);
    r.u[3] = __builtin_amdgcn_perm(__float_as_uint(b.w), __float_as_uint(b.z), 0x07060302u);
    return r.v;
}

// ---------------------------------------------------------------------------
// K2: pipelined global_load_lds MFMA screen (T3/T4 2-phase).
// 512 blocks x 256 thr; block handles CPB=32 candidates of one batch row.
// LDS: 2 x 32KB doc buffers. Wave wv stages & computes doc-row quarter
// [wv*16, wv*16+16). Granule-XOR swizzle c^=(r&7) applied on the GLOBAL
// source (rule #21: linear LDS dest) and on the ds_read addresses.
// Counted vmcnt(8): next candidate's 8 staging loads stay in flight.
// ---------------------------------------------------------------------------
__global__ __launch_bounds__(256, 2) void k_screen_mfma(
    const unsigned short* __restrict__ qhi,  // [BB][QL][HD] bf16(q)
    const float* __restrict__ vecs,          // [n_docs][DLN][HD] f32
    const int* __restrict__ pids,            // [BB][NC]
    float* __restrict__ scores)              // [BB][NC]
{
    const int t    = threadIdx.x;
    const int lane = t & 63;
    const int wv   = t >> 6;                 // doc-row quarter
    const int blk  = blockIdx.x;             // 512 blocks
    const int b    = blk >> 5;               // 32 blocks per batch row
    const int n0   = (blk & 31) * CPB;

    __shared__ float sdoc[2][DLN * HD];      // 2 x 32 KB
    __shared__ float red[2][4][QL];          // parity-double-buffered reduce

    // Preload this block's 32 pids into wave registers (lane&31 -> cand).
    const int pid_l = pids[b * NC + n0 + (lane & 31)];

    // Precompute per-lane staging source offsets (floats), j = 0..7.
    // LDS dest granule d = wv*512 + j*64 + lane (linear). Source granule:
    // r = d>>5, s = d&31, c = s ^ (r&7)  ->  off = (r*32 + c)*4 floats.
    int soff[8];
#pragma unroll
    for (int j = 0; j < 8; ++j) {
        int rd = wv * 16 + j * 2 + (lane >> 5);
        int c  = (lane & 31) ^ (rd & 7);
        soff[j] = (rd * 32 + c) * 4;
    }

    // Read addressing: lane reads row r = wv*16 + r16, 32B at col ks*32+kb*8,
    // with the same granule XOR: float off = rbase + ((ks*32+kb*8) ^ rx).
    const int r16   = lane & 15;
    const int kb    = lane >> 4;
    const int rbase = (wv * 16 + r16) * HD;
    const int rx    = (r16 & 7) * 4;

    // A fragments (R7-proven offsets); force completion before the pipeline.
    bf16x8 qf[2][4];
#pragma unroll
    for (int m = 0; m < 2; ++m)
#pragma unroll
        for (int ks = 0; ks < 4; ++ks) {
            int off = ((b * QL + m * 16 + r16) * HD + ks * 32 + kb * 8);
            qf[m][ks] = *(const bf16x8*)(qhi + off);
        }
    asm volatile("s_waitcnt vmcnt(0)" ::: "memory");

    // Prologue: stage candidate 0 into buffer 0.
    {
        int pid0 = __shfl(pid_l, 0);
        const float* dbase = vecs + (size_t)(pid0 < 0 ? 0 : pid0) * (DLN * HD);
#pragma unroll
        for (int j = 0; j < 8; ++j)
            __builtin_amdgcn_global_load_lds(
                (const __attribute__((address_space(1))) void*)(dbase + soff[j]),
                (__attribute__((address_space(3))) void*)(&sdoc[0][wv * 2048 + j * 256]),
                16, 0, 0);
    }

    for (int i = 0; i < CPB; ++i) {
        const int cur = i & 1;

        // Stage candidate i+1 into the other buffer; keep its 8 loads pending.
        if (i + 1 < CPB) {
            int pid1 = __shfl(pid_l, i + 1);
            const float* dbase = vecs + (size_t)(pid1 < 0 ? 0 : pid1) * (DLN * HD);
#pragma unroll
            for (int j = 0; j < 8; ++j)
                __builtin_amdgcn_global_load_lds(
                    (const __attribute__((address_space(1))) void*)(dbase + soff[j]),
                    (__attribute__((address_space(3))) void*)(&sdoc[cur ^ 1][wv * 2048 + j * 256]),
                    16, 0, 0);
            asm volatile("s_waitcnt vmcnt(8)" ::: "memory");   // cand i ready
        } else {
            asm volatile("s_waitcnt vmcnt(0)" ::: "memory");
        }

        // Compute candidate i from sdoc[cur] (wave reads only its own rows).
        const float* dbuf = &sdoc[cur][0];
        f32x4 acc[2] = {};
#pragma unroll
        for (int ks = 0; ks < 4; ++ks) {
            int o0 = rbase + ((ks * 32 + kb * 8) ^ rx);
            float4 x0 = *(const float4*)(dbuf + o0);
            float4 x1 = *(const float4*)(dbuf + (o0 ^ 4));
            bf16x8 bh = cvt8_rtz(x0, x1);
            acc[0] = __builtin_amdgcn_mfma_f32_16x16x32_bf16(qf[0][ks], bh, acc[0], 0, 0, 0);
            acc[1] = __builtin_amdgcn_mfma_f32_16x16x32_bf16(qf[1][ks], bh, acc[1], 0, 0, 0);
        }

        // Row-max over this wave's 16 doc cols; write 32 q-row maxes to red.
#pragma unroll
        for (int m = 0; m < 2; ++m)
#pragma unroll
            for (int r = 0; r < 4; ++r) {
                float x = acc[m][r];
                x = fmaxf(x, __shfl_xor(x, 1));
                x = fmaxf(x, __shfl_xor(x, 2));
                x = fmaxf(x, __shfl_xor(x, 4));
                x = fmaxf(x, __shfl_xor(x, 8));
                if (r16 == 0) red[cur][wv][m * 16 + kb * 4 + r] = x;
            }
        asm volatile("s_waitcnt lgkmcnt(0)" ::: "memory");
        __builtin_amdgcn_s_barrier();                 // red[cur] complete

        if (t < 32) {                                 // wave 0 finalizes
            float v = fmaxf(fmaxf(red[cur][0][t], red[cur][1][t]),
                            fmaxf(red[cur][2][t], red[cur][3][t]));
            v += __shfl_xor(v, 1);
            v += __shfl_xor(v, 2);
            v += __shfl_xor(v, 4);
            v += __shfl_xor(v, 8);
            v += __shfl_xor(v, 16);
            int pidi = __shfl(pid_l, i);
            if (t == 0)
                scores[b * NC + n0 + i] =
                    (pidi < 0) ? -__builtin_inff() : v * (1.0f / 32.0f);
        }
        // No trailing barrier: red parity + the per-iteration barrier keep
        // waves within one iteration; doc buffers have no cross-wave readers.
    }
}

// ---------------------------------------------------------------------------
// K3a: per-row full bitonic sort of (f32 score desc, idx asc); keep top RK.
// (R9 version, proven.)
// ---------------------------------------------------------------------------
__global__ __launch_bounds__(1024) void k_select(
    const float* __restrict__ scores, int* __restrict__ sel)
{
    const int b = blockIdx.x;
    const int t = threadIdx.x;
    __shared__ float ss[NC];
    __shared__ int   si[NC];

    ss[t] = scores[b * NC + t];
    si[t] = t;
    __syncthreads();

    for (int k2 = 2; k2 <= NC; k2 <<= 1) {
        for (int j = k2 >> 1; j > 0; j >>= 1) {
            int ixj = t ^ j;
            if (ixj > t) {
                float as = ss[t], bs = ss[ixj];
                int   ai = si[t], bi = si[ixj];
                bool a_first = (as > bs) || (as == bs && ai < bi);
                bool desc = ((t & k2) == 0);
                if (desc ? !a_first : a_first) { ss[t] = bs; si[t] = bi; ss[ixj] = as; si[ixj] = ai; }
            }
            __syncthreads();
        }
    }
    if (t < RK) sel[b * RK + t] = si[t];
}

// ---------------------------------------------------------------------------
// K3b: f64-MFMA rescore (R9-proven, unchanged). One block per candidate.
// ---------------------------------------------------------------------------
#define DPAD (HD + 4)   // 132: float4-aligned, <=2-way LDS bank aliasing

__global__ __launch_bounds__(256) void k_rescore_mfma(
    const float* __restrict__ q,     // [BB][QL][HD]
    const float* __restrict__ vecs,  // [n_docs][DLN][HD]
    const int* __restrict__ pids,    // [BB][NC]
    const int* __restrict__ sel,     // [BB][RK]
    double* __restrict__ resc)       // [BB][RK]
{
    const int r = blockIdx.x, b = blockIdx.y;
    const int t = threadIdx.x;
    const int n = sel[b * RK + r];
    const int pid = pids[b * NC + n];
    if (pid < 0) {
        if (t == 0) resc[b * RK + r] = -__builtin_inf();
        return;
    }

    __shared__ float  sq[QL][DPAD];      // 16.9 KB
    __shared__ float  sdoc[DLN][DPAD];   // 33.8 KB
    __shared__ double red[4][QL];        // 1 KB

    {
        const float4* src = (const float4*)(q + (size_t)b * QL * HD);
        for (int i = t; i < QL * HD / 4; i += 256) {
            int row = i >> 5, c4 = (i & 31) << 2;
            *(float4*)&sq[row][c4] = src[i];
        }
    }
    {
        const float4* src = (const float4*)(vecs + (size_t)pid * DLN * HD);
        for (int i = t; i < DLN * HD / 4; i += 256) {
            int row = i >> 5, c4 = (i & 31) << 2;
            *(float4*)&sdoc[row][c4] = src[i];
        }
    }
    __syncthreads();

    const int lane = t & 63;
    const int wv   = t >> 6;             // doc-column quarter
    const int c16  = lane & 15;
    const int kq   = lane >> 4;          // k within the K=4 step

    f64x4 acc[2] = {};
#pragma unroll 4
    for (int ks = 0; ks < 32; ++ks) {
        double bv = (double)sdoc[wv * 16 + c16][ks * 4 + kq];
        double a0 = (double)sq[c16][ks * 4 + kq];
        double a1 = (double)sq[16 + c16][ks * 4 + kq];
        acc[0] = __builtin_amdgcn_mfma_f64_16x16x4f64(a0, bv, acc[0], 0, 0, 0);
        acc[1] = __builtin_amdgcn_mfma_f64_16x16x4f64(a1, bv, acc[1], 0, 0, 0);
    }

#pragma unroll
    for (int m = 0; m < 2; ++m)
#pragma unroll
        for (int rr = 0; rr < 4; ++rr) {
            double x = acc[m][rr];
            x = fmax(x, __shfl_xor(x, 1));
            x = fmax(x, __shfl_xor(x, 2));
            x = fmax(x, __shfl_xor(x, 4));
            x = fmax(x, __shfl_xor(x, 8));
            if (c16 == 0) red[wv][m * 16 + kq * 4 + rr] = x;
        }
    __syncthreads();

    if (t < 32) {
        double v = fmax(fmax(red[0][t], red[1][t]), fmax(red[2][t], red[3][t]));
        v += __shfl_xor(v, 1);
        v += __shfl_xor(v, 2);
        v += __shfl_xor(v, 4);
        v += __shfl_xor(v, 8);
        v += __shfl_xor(v, 16);
        if (t == 0) resc[b * RK + r] = v * (1.0 / 32.0);
    }
}

// ---------------------------------------------------------------------------
// K3c: sort the RK rescored candidates by (f64 score desc, idx asc); emit k.
// ---------------------------------------------------------------------------
__global__ __launch_bounds__(RK) void k_final(
    const double* __restrict__ resc, const int* __restrict__ sel,
    const int* __restrict__ pids, float* __restrict__ out, int k)
{
    const int b = blockIdx.x;
    const int t = threadIdx.x;
    __shared__ double ss[RK];
    __shared__ int    sn[RK];

    ss[t] = resc[b * RK + t];
    sn[t] = sel[b * RK + t];
    __syncthreads();

    for (int k2 = 2; k2 <= RK; k2 <<= 1) {
        for (int j = k2 >> 1; j > 0; j >>= 1) {
            int ixj = t ^ j;
            if (ixj > t) {
                double as = ss[t], bs = ss[ixj];
                int    ai = sn[t], bi = sn[ixj];
                bool a_first = (as > bs) || (as == bs && ai < bi);
                bool desc = ((t & k2) == 0);
                if (desc ? !a_first : a_first) { ss[t] = bs; sn[t] = bi; ss[ixj] = as; sn[ixj] = ai; }
            }
            __syncthreads();
        }
    }

    if (t < k) {
        out[b * k + t]          = (float)pids[b * NC + sn[t]];  // top_pids
        out[BB * k + b * k + t] = (float)ss[t];                 // top_scores
    }
}

// ---------------------------------------------------------------------------
extern "C" void kernel_launch(void* const* d_in, const int* in_sizes, int n_in,
                              void* d_out, int out_size, void* d_ws, size_t ws_size,
                              hipStream_t stream)
{
    const float* q_vectors = (const float*)d_in[0];   // [16][32][128] f32
    const int*   topk_idx  = (const int*)d_in[1];     // [16][1024] i32
    const float* vectors   = (const float*)d_in[2];   // [20000][64][128] f32
    const int*   emb2pid   = (const int*)d_in[3];     // [1280000] i32

    const int n_emb  = in_sizes[3];
    const int n_docs = in_sizes[2] / (DLN * HD);
    const int k      = out_size / (2 * BB);           // 100

    char* ws = (char*)d_ws;
    int*    pids_ws   = (int*)ws;      ws += BB * NC * sizeof(int);      // 64 KB
    float*  scores_ws = (float*)ws;    ws += BB * NC * sizeof(float);    // 64 KB
    int*    sel_ws    = (int*)ws;      ws += BB * RK * sizeof(int);      // 8 KB
    double* resc_ws   = (double*)ws;   ws += BB * RK * sizeof(double);   // 16 KB
    unsigned short* qhi_ws = (unsigned short*)ws;                        // 128 KB

    k_qprep<<<dim3(BB * QL * HD / 256), dim3(256), 0, stream>>>(
        q_vectors, qhi_ws);

    k_gather_sort_dedup<<<dim3(BB), dim3(NC), 0, stream>>>(
        topk_idx, emb2pid, n_emb, n_docs, pids_ws);

    k_screen_mfma<<<dim3(BB * NC / CPB), dim3(256), 0, stream>>>(
        qhi_ws, vectors, pids_ws, scores_ws);

    k_select<<<dim3(BB), dim3(NC), 0, stream>>>(scores_ws, sel_ws);

    k_rescore_mfma<<<dim3(RK, BB), dim3(256), 0, stream>>>(
        q_vectors, vectors, pids_ws, sel_ws, resc_ws);

    k_final<<<dim3(BB), dim3(RK), 0, stream>>>(
        resc_ws, sel_ws, pids_ws, (float*)d_out, k);
}

// Round 12
// 162.668 us; speedup vs baseline: 1.1045x; 1.1045x over previous
//
#include <hip/hip_runtime.h>
#include <hip/hip_bf16.h>
#include <math.h>

#define BB   16      // batch
#define NC   1024    // candidates per query row
#define QL   32      // query tokens
#define HD   128     // embed dim
#define DLN  64      // doc tokens per doc
#define RK   128     // rescore set size per row (pow2, >= k=100 with margin)
#define NPW  2       // candidates per wave in the screen kernel

typedef __attribute__((ext_vector_type(8))) short bf16x8;   // 8 bf16 (4 VGPRs)
typedef __attribute__((ext_vector_type(4))) float f32x4;    // MFMA accumulator
typedef __attribute__((ext_vector_type(4))) double f64x4;   // f64 MFMA accum

// ---------------------------------------------------------------------------
// K0: precompute bf16(q) for the MFMA screen.
// ---------------------------------------------------------------------------
__global__ __launch_bounds__(256) void k_qprep(
    const float* __restrict__ q, unsigned short* __restrict__ qhi)
{
    int i = blockIdx.x * 256 + threadIdx.x;          // BB*QL*HD = 65536
    float v = q[i];
    __hip_bfloat16 h = __float2bfloat16(v);
    qhi[i] = *reinterpret_cast<unsigned short*>(&h);
}

// ---------------------------------------------------------------------------
// K1: pids = emb2pid[topk]; validate; per-row DESC bitonic sort; dedup.
// Hybrid bitonic: register-resident element per thread; j<64 phases via
// __shfl_xor (no barrier, no LDS); j>=64 via LDS (2 barriers). 45 of 55
// phases become barrier-free. Equal values -> no swap (symmetric lv/uv
// formulation), so the network is a valid permutation.
// ---------------------------------------------------------------------------
__global__ __launch_bounds__(1024) void k_gather_sort_dedup(
    const int* __restrict__ topk, const int* __restrict__ emb2pid,
    int n_emb, int n_docs, int* __restrict__ pids_out)
{
    const int b = blockIdx.x;
    const int t = threadIdx.x;
    __shared__ int s[NC];

    int idx = topk[b * NC + t];
    int v = (idx >= 0 && idx < n_emb) ? emb2pid[idx] : -1;
    if (v < 0 || v >= n_docs) v = -1;

    for (int k2 = 2; k2 <= NC; k2 <<= 1) {
        for (int j = k2 >> 1; j > 0; j >>= 1) {
            const bool desc = ((t & k2) == 0);
            const bool is_lower = ((t & j) == 0);
            int ov;
            if (j >= 64) {
                s[t] = v;
                __syncthreads();
                ov = s[t ^ j];
                __syncthreads();
            } else {
                ov = __shfl_xor(v, j);
            }
            int lv = is_lower ? v : ov;
            int uv = is_lower ? ov : v;
            bool swap = desc ? (lv < uv) : (lv > uv);
            if (swap) v = ov;
        }
    }
    s[t] = v;
    __syncthreads();
    pids_out[b * NC + t] = (t > 0 && v == s[t - 1]) ? -1 : v;
}

// ---------------------------------------------------------------------------
// Round 8 f32 to bf16 (RNE) -> one bf16x8 fragment.
// ---------------------------------------------------------------------------
__device__ __forceinline__ bf16x8 cvt8(float4 a, float4 c)
{
    float v[8] = {a.x, a.y, a.z, a.w, c.x, c.y, c.z, c.w};
    bf16x8 r;
#pragma unroll
    for (int j = 0; j < 8; ++j) {
        __hip_bfloat16 h = __float2bfloat16(v[j]);
        r[j] = *reinterpret_cast<short*>(&h);
    }
    return r;
}

// ---------------------------------------------------------------------------
// K2: MFMA screening (R9-proven best: register-direct doc loads, no LDS, no
// barriers, launch_bounds(256,4), NPW=2). Screen is memory-roofline-bound
// (~4.5 TB/s effective gather) — R10/R11 showed schedule changes are null.
// ---------------------------------------------------------------------------
__global__ __launch_bounds__(256, 4) void k_screen_mfma(
    const unsigned short* __restrict__ qhi,  // [BB][QL][HD] bf16(q)
    const float* __restrict__ vecs,          // [n_docs][DLN][HD] f32
    const int* __restrict__ pids,            // [BB][NC]
    float* __restrict__ scores)              // [BB][NC]
{
    const int lane = threadIdx.x & 63;
    const int wv   = threadIdx.x >> 6;              // 0..3
    const int bk   = blockIdx.x;
    const int BPR  = NC / (4 * NPW);                // blocks per batch row
    const int b    = bk / BPR;
    const int nb   = (bk % BPR) * (4 * NPW) + wv * NPW;

    const int r16 = lane & 15;
    const int kb  = lane >> 4;

    bf16x8 qf[2][4];
#pragma unroll
    for (int m = 0; m < 2; ++m)
#pragma unroll
        for (int ks = 0; ks < 4; ++ks) {
            int off = ((b * QL + m * 16 + r16) * HD + ks * 32 + kb * 8);
            qf[m][ks] = *(const bf16x8*)(qhi + off);
        }

    for (int nn = 0; nn < NPW; ++nn) {
        const int n = nb + nn;
        const int pid = pids[b * NC + n];
        if (pid < 0) {
            if (lane == 0) scores[b * NC + n] = -__builtin_inff();
            continue;
        }
        const float* dbase = vecs + (size_t)pid * (DLN * HD);

        f32x4 acc[2][4] = {};
#pragma unroll
        for (int ks = 0; ks < 4; ++ks) {
#pragma unroll
            for (int nt = 0; nt < 4; ++nt) {
                const float* p = dbase + (nt * 16 + r16) * HD + ks * 32 + kb * 8;
                float4 x0 = *(const float4*)p;
                float4 x1 = *(const float4*)(p + 4);
                bf16x8 bh = cvt8(x0, x1);
#pragma unroll
                for (int m = 0; m < 2; ++m)
                    acc[m][nt] = __builtin_amdgcn_mfma_f32_16x16x32_bf16(
                        qf[m][ks], bh, acc[m][nt], 0, 0, 0);
            }
        }

        float s = 0.f;
#pragma unroll
        for (int m = 0; m < 2; ++m) {
#pragma unroll
            for (int r = 0; r < 4; ++r) {
                float x = fmaxf(fmaxf(acc[m][0][r], acc[m][1][r]),
                                fmaxf(acc[m][2][r], acc[m][3][r]));
                x = fmaxf(x, __shfl_xor(x, 1));
                x = fmaxf(x, __shfl_xor(x, 2));
                x = fmaxf(x, __shfl_xor(x, 4));
                x = fmaxf(x, __shfl_xor(x, 8));
                s += x;
            }
        }
        s += __shfl_xor(s, 16);
        s += __shfl_xor(s, 32);
        if (lane == 0) scores[b * NC + n] = s * (1.0f / 32.0f);
    }
}

// ---------------------------------------------------------------------------
// K3a: per-row top-RK select via hybrid bitonic sort of (score desc, idx asc).
// Same hybrid scheme as K1; comparator is a strict total order (idx distinct),
// symmetric lower_first on both partners -> exact exchange.
// ---------------------------------------------------------------------------
__global__ __launch_bounds__(1024) void k_select(
    const float* __restrict__ scores, int* __restrict__ sel)
{
    const int b = blockIdx.x;
    const int t = threadIdx.x;
    __shared__ float ss[NC];
    __shared__ int   si[NC];

    float v  = scores[b * NC + t];
    int   id = t;

    for (int k2 = 2; k2 <= NC; k2 <<= 1) {
        for (int j = k2 >> 1; j > 0; j >>= 1) {
            const bool desc = ((t & k2) == 0);
            const bool is_lower = ((t & j) == 0);
            float ov; int oi;
            if (j >= 64) {
                ss[t] = v; si[t] = id;
                __syncthreads();
                ov = ss[t ^ j]; oi = si[t ^ j];
                __syncthreads();
            } else {
                ov = __shfl_xor(v, j);
                oi = __shfl_xor(id, j);
            }
            float lv = is_lower ? v : ov;  int li = is_lower ? id : oi;
            float uv = is_lower ? ov : v;  int ui = is_lower ? oi : id;
            bool lower_first = (lv > uv) || (lv == uv && li < ui);
            bool swap = desc ? !lower_first : lower_first;
            if (swap) { v = ov; id = oi; }
        }
    }
    if (t < RK) sel[b * RK + t] = id;
}

// ---------------------------------------------------------------------------
// K3b: f64-MFMA rescore (R9-proven, unchanged). One block per candidate.
// ---------------------------------------------------------------------------
#define DPAD (HD + 4)   // 132: float4-aligned, <=2-way LDS bank aliasing

__global__ __launch_bounds__(256) void k_rescore_mfma(
    const float* __restrict__ q,     // [BB][QL][HD]
    const float* __restrict__ vecs,  // [n_docs][DLN][HD]
    const int* __restrict__ pids,    // [BB][NC]
    const int* __restrict__ sel,     // [BB][RK]
    double* __restrict__ resc)       // [BB][RK]
{
    const int r = blockIdx.x, b = blockIdx.y;
    const int t = threadIdx.x;
    const int n = sel[b * RK + r];
    const int pid = pids[b * NC + n];
    if (pid < 0) {
        if (t == 0) resc[b * RK + r] = -__builtin_inf();
        return;
    }

    __shared__ float  sq[QL][DPAD];      // 16.9 KB
    __shared__ float  sdoc[DLN][DPAD];   // 33.8 KB
    __shared__ double red[4][QL];        // 1 KB

    {
        const float4* src = (const float4*)(q + (size_t)b * QL * HD);
        for (int i = t; i < QL * HD / 4; i += 256) {
            int row = i >> 5, c4 = (i & 31) << 2;
            *(float4*)&sq[row][c4] = src[i];
        }
    }
    {
        const float4* src = (const float4*)(vecs + (size_t)pid * DLN * HD);
        for (int i = t; i < DLN * HD / 4; i += 256) {
            int row = i >> 5, c4 = (i & 31) << 2;
            *(float4*)&sdoc[row][c4] = src[i];
        }
    }
    __syncthreads();

    const int lane = t & 63;
    const int wv   = t >> 6;             // doc-column quarter
    const int c16  = lane & 15;
    const int kq   = lane >> 4;          // k within the K=4 step

    f64x4 acc[2] = {};
#pragma unroll 4
    for (int ks = 0; ks < 32; ++ks) {
        double bv = (double)sdoc[wv * 16 + c16][ks * 4 + kq];
        double a0 = (double)sq[c16][ks * 4 + kq];
        double a1 = (double)sq[16 + c16][ks * 4 + kq];
        acc[0] = __builtin_amdgcn_mfma_f64_16x16x4f64(a0, bv, acc[0], 0, 0, 0);
        acc[1] = __builtin_amdgcn_mfma_f64_16x16x4f64(a1, bv, acc[1], 0, 0, 0);
    }

#pragma unroll
    for (int m = 0; m < 2; ++m)
#pragma unroll
        for (int rr = 0; rr < 4; ++rr) {
            double x = acc[m][rr];
            x = fmax(x, __shfl_xor(x, 1));
            x = fmax(x, __shfl_xor(x, 2));
            x = fmax(x, __shfl_xor(x, 4));
            x = fmax(x, __shfl_xor(x, 8));
            if (c16 == 0) red[wv][m * 16 + kq * 4 + rr] = x;
        }
    __syncthreads();

    if (t < 32) {
        double v = fmax(fmax(red[0][t], red[1][t]), fmax(red[2][t], red[3][t]));
        v += __shfl_xor(v, 1);
        v += __shfl_xor(v, 2);
        v += __shfl_xor(v, 4);
        v += __shfl_xor(v, 8);
        v += __shfl_xor(v, 16);
        if (t == 0) resc[b * RK + r] = v * (1.0 / 32.0);
    }
}

// ---------------------------------------------------------------------------
// K3c: sort the RK rescored candidates by (f64 score desc, idx asc); emit k.
// ---------------------------------------------------------------------------
__global__ __launch_bounds__(RK) void k_final(
    const double* __restrict__ resc, const int* __restrict__ sel,
    const int* __restrict__ pids, float* __restrict__ out, int k)
{
    const int b = blockIdx.x;
    const int t = threadIdx.x;
    __shared__ double ss[RK];
    __shared__ int    sn[RK];

    ss[t] = resc[b * RK + t];
    sn[t] = sel[b * RK + t];
    __syncthreads();

    for (int k2 = 2; k2 <= RK; k2 <<= 1) {
        for (int j = k2 >> 1; j > 0; j >>= 1) {
            int ixj = t ^ j;
            if (ixj > t) {
                double as = ss[t], bs = ss[ixj];
                int    ai = sn[t], bi = sn[ixj];
                bool a_first = (as > bs) || (as == bs && ai < bi);
                bool desc = ((t & k2) == 0);
                if (desc ? !a_first : a_first) { ss[t] = bs; sn[t] = bi; ss[ixj] = as; sn[ixj] = ai; }
            }
            __syncthreads();
        }
    }

    if (t < k) {
        out[b * k + t]          = (float)pids[b * NC + sn[t]];  // top_pids
        out[BB * k + b * k + t] = (float)ss[t];                 // top_scores
    }
}

// ---------------------------------------------------------------------------
extern "C" void kernel_launch(void* const* d_in, const int* in_sizes, int n_in,
                              void* d_out, int out_size, void* d_ws, size_t ws_size,
                              hipStream_t stream)
{
    const float* q_vectors = (const float*)d_in[0];   // [16][32][128] f32
    const int*   topk_idx  = (const int*)d_in[1];     // [16][1024] i32
    const float* vectors   = (const float*)d_in[2];   // [20000][64][128] f32
    const int*   emb2pid   = (const int*)d_in[3];     // [1280000] i32

    const int n_emb  = in_sizes[3];
    const int n_docs = in_sizes[2] / (DLN * HD);
    const int k      = out_size / (2 * BB);           // 100

    char* ws = (char*)d_ws;
    int*    pids_ws   = (int*)ws;      ws += BB * NC * sizeof(int);      // 64 KB
    float*  scores_ws = (float*)ws;    ws += BB * NC * sizeof(float);    // 64 KB
    int*    sel_ws    = (int*)ws;      ws += BB * RK * sizeof(int);      // 8 KB
    double* resc_ws   = (double*)ws;   ws += BB * RK * sizeof(double);   // 16 KB
    unsigned short* qhi_ws = (unsigned short*)ws;                        // 128 KB

    k_qprep<<<dim3(BB * QL * HD / 256), dim3(256), 0, stream>>>(
        q_vectors, qhi_ws);

    k_gather_sort_dedup<<<dim3(BB), dim3(NC), 0, stream>>>(
        topk_idx, emb2pid, n_emb, n_docs, pids_ws);

    k_screen_mfma<<<dim3(BB * NC / (4 * NPW)), dim3(256), 0, stream>>>(
        qhi_ws, vectors, pids_ws, scores_ws);

    k_select<<<dim3(BB), dim3(NC), 0, stream>>>(scores_ws, sel_ws);

    k_rescore_mfma<<<dim3(RK, BB), dim3(256), 0, stream>>>(
        q_vectors, vectors, pids_ws, sel_ws, resc_ws);

    k_final<<<dim3(BB), dim3(RK), 0, stream>>>(
        resc_ws, sel_ws, pids_ws, (float*)d_out, k);
}

// Round 14
// 156.723 us; speedup vs baseline: 1.1464x; 1.0379x over previous
//
#include <hip/hip_runtime.h>
#include <hip/hip_bf16.h>
#include <math.h>

#define BB   16      // batch
#define NC   1024    // candidates per query row
#define QL   32      // query tokens
#define HD   128     // embed dim
#define DLN  64      // doc tokens per doc
#define RK   128     // rescore set size per row (pow2, >= k=100 with margin)
#define NPW  2       // candidates per wave in the screen kernel

typedef __attribute__((ext_vector_type(8))) short bf16x8;   // 8 bf16 (4 VGPRs)
typedef __attribute__((ext_vector_type(4))) float f32x4;    // MFMA accumulator
typedef __attribute__((ext_vector_type(4))) double f64x4;   // f64 MFMA accum

// ---------------------------------------------------------------------------
// K1: fused qprep + gather/sort/dedup. Block b first converts q row-block b
// (QL*HD = 4096 elems) to bf16 (vectorized float4 -> ushort4), then does the
// per-row DESC hybrid register/LDS bitonic sort + dedup (R12-proven).
// The screen reads qhi only after this kernel, so ordering is preserved.
// ---------------------------------------------------------------------------
__global__ __launch_bounds__(1024) void k_gather_sort_dedup(
    const int* __restrict__ topk, const int* __restrict__ emb2pid,
    const float* __restrict__ q, unsigned short* __restrict__ qhi,
    int n_emb, int n_docs, int* __restrict__ pids_out)
{
    const int b = blockIdx.x;
    const int t = threadIdx.x;
    __shared__ int s[NC];

    // qprep: thread t converts elements [t*4, t*4+4) of this row's q slab.
    {
        const int base = b * (QL * HD) + t * 4;
        float4 x = *(const float4*)(q + base);
        ushort4 o;
        __hip_bfloat16 h0 = __float2bfloat16(x.x);
        __hip_bfloat16 h1 = __float2bfloat16(x.y);
        __hip_bfloat16 h2 = __float2bfloat16(x.z);
        __hip_bfloat16 h3 = __float2bfloat16(x.w);
        o.x = *reinterpret_cast<unsigned short*>(&h0);
        o.y = *reinterpret_cast<unsigned short*>(&h1);
        o.z = *reinterpret_cast<unsigned short*>(&h2);
        o.w = *reinterpret_cast<unsigned short*>(&h3);
        *(ushort4*)(qhi + base) = o;
    }

    int idx = topk[b * NC + t];
    int v = (idx >= 0 && idx < n_emb) ? emb2pid[idx] : -1;
    if (v < 0 || v >= n_docs) v = -1;

    for (int k2 = 2; k2 <= NC; k2 <<= 1) {
        for (int j = k2 >> 1; j > 0; j >>= 1) {
            const bool desc = ((t & k2) == 0);
            const bool is_lower = ((t & j) == 0);
            int ov;
            if (j >= 64) {
                s[t] = v;
                __syncthreads();
                ov = s[t ^ j];
                __syncthreads();
            } else {
                ov = __shfl_xor(v, j);
            }
            int lv = is_lower ? v : ov;
            int uv = is_lower ? ov : v;
            bool swap = desc ? (lv < uv) : (lv > uv);
            if (swap) v = ov;
        }
    }
    s[t] = v;
    __syncthreads();
    pids_out[b * NC + t] = (t > 0 && v == s[t - 1]) ? -1 : v;
}

// ---------------------------------------------------------------------------
// Round 8 f32 to bf16 (RNE) -> one bf16x8 fragment.
// ---------------------------------------------------------------------------
__device__ __forceinline__ bf16x8 cvt8(float4 a, float4 c)
{
    float v[8] = {a.x, a.y, a.z, a.w, c.x, c.y, c.z, c.w};
    bf16x8 r;
#pragma unroll
    for (int j = 0; j < 8; ++j) {
        __hip_bfloat16 h = __float2bfloat16(v[j]);
        r[j] = *reinterpret_cast<short*>(&h);
    }
    return r;
}

// ---------------------------------------------------------------------------
// K2: MFMA screening (R9/R12-proven best: register-direct doc loads, no LDS,
// no barriers, launch_bounds(256,4), NPW=2). Screen is memory-path-bound
// (~4.9 TB/s blended gather): R10 (occupancy/ILP), R11 (counted-vmcnt
// pipeline), R13 (barrier-free pipeline) were null/broken — keep this one.
// ---------------------------------------------------------------------------
__global__ __launch_bounds__(256, 4) void k_screen_mfma(
    const unsigned short* __restrict__ qhi,  // [BB][QL][HD] bf16(q)
    const float* __restrict__ vecs,          // [n_docs][DLN][HD] f32
    const int* __restrict__ pids,            // [BB][NC]
    float* __restrict__ scores)              // [BB][NC]
{
    const int lane = threadIdx.x & 63;
    const int wv   = threadIdx.x >> 6;              // 0..3
    const int bk   = blockIdx.x;
    const int BPR  = NC / (4 * NPW);                // blocks per batch row
    const int b    = bk / BPR;
    const int nb   = (bk % BPR) * (4 * NPW) + wv * NPW;

    const int r16 = lane & 15;
    const int kb  = lane >> 4;

    bf16x8 qf[2][4];
#pragma unroll
    for (int m = 0; m < 2; ++m)
#pragma unroll
        for (int ks = 0; ks < 4; ++ks) {
            int off = ((b * QL + m * 16 + r16) * HD + ks * 32 + kb * 8);
            qf[m][ks] = *(const bf16x8*)(qhi + off);
        }

    for (int nn = 0; nn < NPW; ++nn) {
        const int n = nb + nn;
        const int pid = pids[b * NC + n];
        if (pid < 0) {
            if (lane == 0) scores[b * NC + n] = -__builtin_inff();
            continue;
        }
        const float* dbase = vecs + (size_t)pid * (DLN * HD);

        f32x4 acc[2][4] = {};
#pragma unroll
        for (int ks = 0; ks < 4; ++ks) {
#pragma unroll
            for (int nt = 0; nt < 4; ++nt) {
                const float* p = dbase + (nt * 16 + r16) * HD + ks * 32 + kb * 8;
                float4 x0 = *(const float4*)p;
                float4 x1 = *(const float4*)(p + 4);
                bf16x8 bh = cvt8(x0, x1);
#pragma unroll
                for (int m = 0; m < 2; ++m)
                    acc[m][nt] = __builtin_amdgcn_mfma_f32_16x16x32_bf16(
                        qf[m][ks], bh, acc[m][nt], 0, 0, 0);
            }
        }

        float s = 0.f;
#pragma unroll
        for (int m = 0; m < 2; ++m) {
#pragma unroll
            for (int r = 0; r < 4; ++r) {
                float x = fmaxf(fmaxf(acc[m][0][r], acc[m][1][r]),
                                fmaxf(acc[m][2][r], acc[m][3][r]));
                x = fmaxf(x, __shfl_xor(x, 1));
                x = fmaxf(x, __shfl_xor(x, 2));
                x = fmaxf(x, __shfl_xor(x, 4));
                x = fmaxf(x, __shfl_xor(x, 8));
                s += x;
            }
        }
        s += __shfl_xor(s, 16);
        s += __shfl_xor(s, 32);
        if (lane == 0) scores[b * NC + n] = s * (1.0f / 32.0f);
    }
}

// ---------------------------------------------------------------------------
// K3a: per-row top-RK select via hybrid bitonic (R12-proven).
// ---------------------------------------------------------------------------
__global__ __launch_bounds__(1024) void k_select(
    const float* __restrict__ scores, int* __restrict__ sel)
{
    const int b = blockIdx.x;
    const int t = threadIdx.x;
    __shared__ float ss[NC];
    __shared__ int   si[NC];

    float v  = scores[b * NC + t];
    int   id = t;

    for (int k2 = 2; k2 <= NC; k2 <<= 1) {
        for (int j = k2 >> 1; j > 0; j >>= 1) {
            const bool desc = ((t & k2) == 0);
            const bool is_lower = ((t & j) == 0);
            float ov; int oi;
            if (j >= 64) {
                ss[t] = v; si[t] = id;
                __syncthreads();
                ov = ss[t ^ j]; oi = si[t ^ j];
                __syncthreads();
            } else {
                ov = __shfl_xor(v, j);
                oi = __shfl_xor(id, j);
            }
            float lv = is_lower ? v : ov;  int li = is_lower ? id : oi;
            float uv = is_lower ? ov : v;  int ui = is_lower ? oi : id;
            bool lower_first = (lv > uv) || (lv == uv && li < ui);
            bool swap = desc ? !lower_first : lower_first;
            if (swap) { v = ov; id = oi; }
        }
    }
    if (t < RK) sel[b * RK + t] = id;
}

// ---------------------------------------------------------------------------
// K3b: f64-MFMA rescore (R9-proven, unchanged). One block per candidate.
// ---------------------------------------------------------------------------
#define DPAD (HD + 4)   // 132: float4-aligned, <=2-way LDS bank aliasing

__global__ __launch_bounds__(256) void k_rescore_mfma(
    const float* __restrict__ q,     // [BB][QL][HD]
    const float* __restrict__ vecs,  // [n_docs][DLN][HD]
    const int* __restrict__ pids,    // [BB][NC]
    const int* __restrict__ sel,     // [BB][RK]
    double* __restrict__ resc)       // [BB][RK]
{
    const int r = blockIdx.x, b = blockIdx.y;
    const int t = threadIdx.x;
    const int n = sel[b * RK + r];
    const int pid = pids[b * NC + n];
    if (pid < 0) {
        if (t == 0) resc[b * RK + r] = -__builtin_inf();
        return;
    }

    __shared__ float  sq[QL][DPAD];      // 16.9 KB
    __shared__ float  sdoc[DLN][DPAD];   // 33.8 KB
    __shared__ double red[4][QL];        // 1 KB

    {
        const float4* src = (const float4*)(q + (size_t)b * QL * HD);
        for (int i = t; i < QL * HD / 4; i += 256) {
            int row = i >> 5, c4 = (i & 31) << 2;
            *(float4*)&sq[row][c4] = src[i];
        }
    }
    {
        const float4* src = (const float4*)(vecs + (size_t)pid * DLN * HD);
        for (int i = t; i < DLN * HD / 4; i += 256) {
            int row = i >> 5, c4 = (i & 31) << 2;
            *(float4*)&sdoc[row][c4] = src[i];
        }
    }
    __syncthreads();

    const int lane = t & 63;
    const int wv   = t >> 6;             // doc-column quarter
    const int c16  = lane & 15;
    const int kq   = lane >> 4;          // k within the K=4 step

    f64x4 acc[2] = {};
#pragma unroll 4
    for (int ks = 0; ks < 32; ++ks) {
        double bv = (double)sdoc[wv * 16 + c16][ks * 4 + kq];
        double a0 = (double)sq[c16][ks * 4 + kq];
        double a1 = (double)sq[16 + c16][ks * 4 + kq];
        acc[0] = __builtin_amdgcn_mfma_f64_16x16x4f64(a0, bv, acc[0], 0, 0, 0);
        acc[1] = __builtin_amdgcn_mfma_f64_16x16x4f64(a1, bv, acc[1], 0, 0, 0);
    }

#pragma unroll
    for (int m = 0; m < 2; ++m)
#pragma unroll
        for (int rr = 0; rr < 4; ++rr) {
            double x = acc[m][rr];
            x = fmax(x, __shfl_xor(x, 1));
            x = fmax(x, __shfl_xor(x, 2));
            x = fmax(x, __shfl_xor(x, 4));
            x = fmax(x, __shfl_xor(x, 8));
            if (c16 == 0) red[wv][m * 16 + kq * 4 + rr] = x;
        }
    __syncthreads();

    if (t < 32) {
        double v = fmax(fmax(red[0][t], red[1][t]), fmax(red[2][t], red[3][t]));
        v += __shfl_xor(v, 1);
        v += __shfl_xor(v, 2);
        v += __shfl_xor(v, 4);
        v += __shfl_xor(v, 8);
        v += __shfl_xor(v, 16);
        if (t == 0) resc[b * RK + r] = v * (1.0 / 32.0);
    }
}

// ---------------------------------------------------------------------------
// K3c: sort the RK rescored candidates by (f64 score desc, idx asc); emit k.
// ---------------------------------------------------------------------------
__global__ __launch_bounds__(RK) void k_final(
    const double* __restrict__ resc, const int* __restrict__ sel,
    const int* __restrict__ pids, float* __restrict__ out, int k)
{
    const int b = blockIdx.x;
    const int t = threadIdx.x;
    __shared__ double ss[RK];
    __shared__ int    sn[RK];

    ss[t] = resc[b * RK + t];
    sn[t] = sel[b * RK + t];
    __syncthreads();

    for (int k2 = 2; k2 <= RK; k2 <<= 1) {
        for (int j = k2 >> 1; j > 0; j >>= 1) {
            int ixj = t ^ j;
            if (ixj > t) {
                double as = ss[t], bs = ss[ixj];
                int    ai = sn[t], bi = sn[ixj];
                bool a_first = (as > bs) || (as == bs && ai < bi);
                bool desc = ((t & k2) == 0);
                if (desc ? !a_first : a_first) { ss[t] = bs; sn[t] = bi; ss[ixj] = as; sn[ixj] = ai; }
            }
            __syncthreads();
        }
    }

    if (t < k) {
        out[b * k + t]          = (float)pids[b * NC + sn[t]];  // top_pids
        out[BB * k + b * k + t] = (float)ss[t];                 // top_scores
    }
}

// ---------------------------------------------------------------------------
extern "C" void kernel_launch(void* const* d_in, const int* in_sizes, int n_in,
                              void* d_out, int out_size, void* d_ws, size_t ws_size,
                              hipStream_t stream)
{
    const float* q_vectors = (const float*)d_in[0];   // [16][32][128] f32
    const int*   topk_idx  = (const int*)d_in[1];     // [16][1024] i32
    const float* vectors   = (const float*)d_in[2];   // [20000][64][128] f32
    const int*   emb2pid   = (const int*)d_in[3];     // [1280000] i32

    const int n_emb  = in_sizes[3];
    const int n_docs = in_sizes[2] / (DLN * HD);
    const int k      = out_size / (2 * BB);           // 100

    char* ws = (char*)d_ws;
    int*    pids_ws   = (int*)ws;      ws += BB * NC * sizeof(int);      // 64 KB
    float*  scores_ws = (float*)ws;    ws += BB * NC * sizeof(float);    // 64 KB
    int*    sel_ws    = (int*)ws;      ws += BB * RK * sizeof(int);      // 8 KB
    double* resc_ws   = (double*)ws;   ws += BB * RK * sizeof(double);   // 16 KB
    unsigned short* qhi_ws = (unsigned short*)ws;                        // 128 KB

    k_gather_sort_dedup<<<dim3(BB), dim3(NC), 0, stream>>>(
        topk_idx, emb2pid, q_vectors, qhi_ws, n_emb, n_docs, pids_ws);

    k_screen_mfma<<<dim3(BB * NC / (4 * NPW)), dim3(256), 0, stream>>>(
        qhi_ws, vectors, pids_ws, scores_ws);

    k_select<<<dim3(BB), dim3(NC), 0, stream>>>(scores_ws, sel_ws);

    k_rescore_mfma<<<dim3(RK, BB), dim3(256), 0, stream>>>(
        q_vectors, vectors, pids_ws, sel_ws, resc_ws);

    k_final<<<dim3(BB), dim3(RK), 0, stream>>>(
        resc_ws, sel_ws, pids_ws, (float*)d_out, k);
}